// Round 7
// baseline (743.805 us; speedup 1.0000x reference)
//
#include <hip/hip_runtime.h>
#include <stdint.h>

#define MTOK 7830      // 30*261 valid token rows
#define MPAD 7936      // padded to 31*256
#define CD   2048
#define VTC  7920      // 30*264 (per-group padded token columns for V^T)
#define AS1 __attribute__((address_space(1)))
#define AS3 __attribute__((address_space(3)))

typedef unsigned short u16;
typedef __bf16 bf16x8 __attribute__((ext_vector_type(8)));
typedef float f32x4 __attribute__((ext_vector_type(4)));
typedef unsigned short u16x8 __attribute__((ext_vector_type(8)));

__device__ __forceinline__ u16 f2bf(float f) {
  unsigned x = __float_as_uint(f);
  return (u16)((x + 0x7fffu + ((x >> 16) & 1u)) >> 16);
}

__device__ __forceinline__ void gld16(const u16* g, u16* l) {
  __builtin_amdgcn_global_load_lds((AS1 const unsigned int*)(g), (AS3 unsigned int*)(l), 16, 0, 0);
}

// ---------------- converts ----------------
__global__ void cvt_tokens(const float* __restrict__ T, u16* __restrict__ O) {
  int row = blockIdx.x;
  size_t base = (size_t)row * CD + threadIdx.x * 8;
  u16x8 o = {0,0,0,0,0,0,0,0};
  if (row < MTOK) {
    const float* s = T + base;
    #pragma unroll
    for (int j = 0; j < 8; ++j) o[j] = f2bf(s[j]);
  }
  *(u16x8*)&O[base] = o;
}

__global__ void cvt_w(const float* __restrict__ Wq, const float* __restrict__ Wk,
                      const float* __restrict__ Wv, const float* __restrict__ Wo,
                      u16* __restrict__ WqkvT, u16* __restrict__ WoT) {
  __shared__ float tile[32][33];
  int k0 = blockIdx.x * 32;
  int n0 = blockIdx.y * 32;
  const float* W; u16* Dst; int nl0, dr0;
  if (n0 < 2048)      { W = Wq; Dst = WqkvT; nl0 = n0;        dr0 = n0; }
  else if (n0 < 4096) { W = Wk; Dst = WqkvT; nl0 = n0 - 2048; dr0 = n0; }
  else if (n0 < 6144) { W = Wv; Dst = WqkvT; nl0 = n0 - 4096; dr0 = n0; }
  else                { W = Wo; Dst = WoT;   nl0 = n0 - 6144; dr0 = n0 - 6144; }
  int tx = threadIdx.x, ty = threadIdx.y;
  #pragma unroll
  for (int i = 0; i < 4; ++i)
    tile[ty + i*8][tx] = W[(size_t)(k0 + ty + i*8) * CD + nl0 + tx];
  __syncthreads();
  #pragma unroll
  for (int i = 0; i < 4; ++i) {
    int n = ty + i*8;
    Dst[(size_t)(dr0 + n) * CD + k0 + tx] = f2bf(tile[tx][n]);
  }
}

// ---------------- pose similarity + topk ----------------
__global__ void posesim(const float* __restrict__ tok, float* __restrict__ sim) {
  int mm = blockIdx.y, nn = blockIdx.x;
  const float* a = tok + (size_t)mm * 261 * CD;
  const float* b = tok + (size_t)nn * 261 * CD;
  int tid = threadIdx.x;
  float p = 0.f;
  for (int j = tid; j < CD; j += 256) p += a[j] * b[j];
  __shared__ float red[256];
  red[tid] = p; __syncthreads();
  for (int s = 128; s > 0; s >>= 1) { if (tid < s) red[tid] += red[tid + s]; __syncthreads(); }
  if (tid == 0) sim[mm*30 + nn] = red[0] + (((mm/5) == (nn/5)) ? 10000.0f : 0.0f);
}

__global__ void topk_bias(const float* __restrict__ sim, float* __restrict__ bias,
                          int* __restrict__ idxo) {
  int m = threadIdx.x;
  if (m >= 30) return;
  float p[30];
  float mx = -1e30f;
  for (int j = 0; j < 30; ++j) { p[j] = sim[m*30 + j]; mx = fmaxf(mx, p[j]); }
  float z = 0.f;
  for (int j = 0; j < 30; ++j) { p[j] = __expf(p[j] - mx); z += p[j]; }
  float inv = 1.0f / z;
  for (int j = 0; j < 30; ++j) p[j] *= inv;
  for (int k = 0; k < 8; ++k) {
    int bj = 0; float bv = p[0];
    for (int j = 1; j < 30; ++j) if (p[j] > bv) { bv = p[j]; bj = j; }
    idxo[m*8 + k] = bj;
    bias[m*8 + k] = logf(bv + 1e-6f);
    p[bj] = -1.0f;
  }
}

// ---------------- GEMM v4: 256x256, BK=64, 8 waves, fine 4-phase K-loop ----
// Staging/gating as v3 (counted vmcnt(8), 8-load flight, 4-phase lead).
// Compute split into 4 phases/(K-tile): each {ds_read 4-8 b128; barrier;
// lgkmcnt(0); setprio(1); 16 MFMA; setprio(0); barrier} -- m201 template.
template<int EPI>
__global__ __launch_bounds__(512) void gemm_bt(
    const u16* __restrict__ A, const u16* __restrict__ Bt,
    u16* __restrict__ Cq, u16* __restrict__ Cv,
    const float* __restrict__ resid, float* __restrict__ Dout, int K)
{
  __shared__ u16 Al[2][256 * 64];
  __shared__ u16 Bl[2][256 * 64];
  int tid = threadIdx.x, lane = tid & 63, wid = tid >> 6;   // wid 0..7
  int lo4 = lane & 15, hi2 = lane >> 4;
  // bijective XCD swizzle (nwg % 8 == 0 for both instantiations)
  int lin = blockIdx.y * gridDim.x + blockIdx.x;
  int q8  = (gridDim.x * gridDim.y) >> 3;
  int lin2 = (lin & 7) * q8 + (lin >> 3);
  int bn = lin2 % gridDim.x, bm = lin2 / gridDim.x;
  int wy = wid >> 2, wx = wid & 3;          // 2M x 4N wave grid
  int r8 = lane >> 3, c8 = lane & 7;

  f32x4 acc[8][4] = {};

  // staging: wave w owns rows w*32..w*32+31 (4 chunks of 8 rows) of A and B tiles
  size_t aofs[4], bofs[4];
  #pragma unroll
  for (int j = 0; j < 4; ++j) {
    int row = wid*32 + j*8 + r8;
    int sw = 8 * (c8 ^ (row & 7));          // XOR-swizzled source, linear LDS dst
    aofs[j] = (size_t)(bm*256 + row) * K + sw;
    bofs[j] = (size_t)(bn*256 + row) * K + sw;
  }
  int ldst = wid * 2048;

  int nK = K >> 6;
  // prologue: stage tiles 0 and 1
  #pragma unroll
  for (int j = 0; j < 4; ++j) {
    gld16(A  + aofs[j], &Al[0][ldst + j*512]);
    gld16(Bt + bofs[j], &Bl[0][ldst + j*512]);
  }
  #pragma unroll
  for (int j = 0; j < 4; ++j) {
    gld16(A  + 64 + aofs[j], &Al[1][ldst + j*512]);
    gld16(Bt + 64 + bofs[j], &Bl[1][ldst + j*512]);
  }

  for (int t = 0; t < nK; ++t) {
    // ---- tile gate: tile t landed; tile t+1's 8 loads may stay in flight
    if (t + 1 < nK) asm volatile("s_waitcnt vmcnt(8)" ::: "memory");
    else            asm volatile("s_waitcnt vmcnt(0)" ::: "memory");
    __builtin_amdgcn_sched_barrier(0);
    __builtin_amdgcn_s_barrier();
    __builtin_amdgcn_sched_barrier(0);

    const u16* Ac = Al[t & 1];
    const u16* Bc = Bl[t & 1];

    bf16x8 bv[4];
    #pragma unroll
    for (int ph = 0; ph < 4; ++ph) {
      const int kk = ph >> 1;               // phases: (kk,mg) = 00,01,10,11
      const int mg = ph & 1;
      if (mg == 0) {
        #pragma unroll
        for (int ni = 0; ni < 4; ++ni) {
          int br = wx*64 + ni*16 + lo4;
          bv[ni] = *(const bf16x8*)&Bc[br*64 + 8*((kk*4 + hi2) ^ (br & 7))];
        }
      }
      bf16x8 av[4];
      #pragma unroll
      for (int mi = 0; mi < 4; ++mi) {
        int ar = wy*128 + mg*64 + mi*16 + lo4;
        av[mi] = *(const bf16x8*)&Ac[ar*64 + 8*((kk*4 + hi2) ^ (ar & 7))];
      }
      __builtin_amdgcn_sched_barrier(0);
      __builtin_amdgcn_s_barrier();         // read burst issued; sync waves
      asm volatile("s_waitcnt lgkmcnt(0)" ::: "memory");
      __builtin_amdgcn_sched_barrier(0);
      __builtin_amdgcn_s_setprio(1);
      #pragma unroll
      for (int mi = 0; mi < 4; ++mi)
        #pragma unroll
        for (int ni = 0; ni < 4; ++ni)
          acc[mg*4 + mi][ni] = __builtin_amdgcn_mfma_f32_16x16x32_bf16(
              av[mi], bv[ni], acc[mg*4 + mi][ni], 0, 0, 0);
      __builtin_amdgcn_s_setprio(0);
      __builtin_amdgcn_sched_barrier(0);
      __builtin_amdgcn_s_barrier();         // phase boundary: bounds wave drift
      __builtin_amdgcn_sched_barrier(0);
    }

    // end of tile t: all waves past ph3 barrier -> slot[t&1] reads done;
    // issue tile t+2 into it (lands during tile t+1's 4 phases)
    if (t + 2 < nK) {
      size_t kn = (size_t)(t + 2) << 6;
      u16* An = Al[t & 1];
      u16* Bn = Bl[t & 1];
      #pragma unroll
      for (int j = 0; j < 4; ++j) {
        gld16(A  + kn + aofs[j], &An[ldst + j*512]);
        gld16(Bt + kn + bofs[j], &Bn[ldst + j*512]);
      }
      __builtin_amdgcn_sched_barrier(0);
    }
  }

  int gm0 = bm*256 + wy*128;
  int gn0 = bn*256 + wx*64;
  #pragma unroll
  for (int mi = 0; mi < 8; ++mi) {
    #pragma unroll
    for (int ni = 0; ni < 4; ++ni) {
      int gmb = gm0 + mi*16 + hi2*4;
      int gn  = gn0 + ni*16 + lo4;
      #pragma unroll
      for (int r = 0; r < 4; ++r) {
        float v = acc[mi][ni][r];
        int gm = gmb + r;
        if (EPI == 0) {
          if (gn < 4096) {
            Cq[(size_t)gm * 4096 + gn] = f2bf(v);
          } else if (gm < MTOK) {
            int g = gm / 261, tk = gm - g * 261;
            Cv[(size_t)(gn - 4096) * VTC + g * 264 + tk] = f2bf(v);
          }
        } else {
          if (gm < MTOK) {
            size_t off = (size_t)gm * CD + gn;
            Dout[off] = resid[off] + v;
          }
        }
      }
    }
  }
}

// ---------------- fused neighbor attention v4 ----------------
__global__ __launch_bounds__(1024) void attn_main(
    const u16* __restrict__ QK,   // [MPAD][4096] bf16 (Q 0..2047 | K 2048..4095)
    const u16* __restrict__ VtG,  // [2048][VTC] bf16 (V^T, per-group stride 264)
    const float* __restrict__ bias, const int* __restrict__ idx,
    u16* __restrict__ AO)         // [MPAD][2048] bf16
{
  int h = blockIdx.x, m = blockIdx.y;
  int tid = threadIdx.x, lane = tid & 63, wid = tid >> 6;   // wid 0..15
  int lo4 = lane & 15, hi2 = lane >> 4;

  __shared__ u16 Kl[2][32 * 256];
  __shared__ u16 Vl[2][256 * 32];
  __shared__ u16 Pl[16][16 * 50];
  __shared__ float bias_s[8];
  __shared__ int   idx_s[8];
  if (tid < 8) {
    bias_s[tid] = bias[m*8 + tid] * 1.4426950408889634f;
    idx_s[tid]  = idx[m*8 + tid];
  }

  int qrow = m*261 + wid*16 + lo4;
  bf16x8 qf[8];
  #pragma unroll
  for (int kk = 0; kk < 8; ++kk)
    qf[kk] = *(const bf16x8*)&QK[(size_t)qrow * 4096 + h*256 + kk*32 + hi2*8];

  int rt = 2*wid + (lane >> 5);
  size_t kof = (size_t)rt * 4096 + 2048 + h*256 + 8*((lane & 31) ^ (rt & 7));
  int vdr = 16*wid + (lane >> 2);
  size_t vof = (size_t)(h*256 + vdr) * VTC + 8*((lane & 3) ^ ((vdr >> 1) & 3));

  f32x4 O[16] = {};
  float srun[4] = {0.f, 0.f, 0.f, 0.f};
  const float SC = 0.09016844f;   // 0.0625 * log2(e)

  {
    int ig0 = idx[m*8];
    gld16(QK + (size_t)(ig0*261) * 4096 + kof, &Kl[0][wid*512]);
    gld16(VtG + (size_t)(ig0*264) + vof,       &Vl[0][wid*512]);
  }

  int vswz = 8 * (hi2 ^ ((lo4 >> 1) & 3));
  int kxb  = (lo4 >> 2) & 1;
  int kswz = 8 * (hi2 ^ (lo4 & 3));

  for (int it = 0; it < 72; ++it) {
    __syncthreads();
    if (it + 1 < 72) {
      int tn = it + 1;
      int gg = tn / 9;
      int tok0n = (tn - gg*9) * 32;
      int ign = idx_s[gg];
      gld16(QK + (size_t)(ign*261 + tok0n) * 4096 + kof, &Kl[tn & 1][wid*512]);
      gld16(VtG + (size_t)(ign*264 + tok0n) + vof,       &Vl[tn & 1][wid*512]);
    }
    {
      int gg = it / 9;
      int tok0 = (it - gg*9) * 32;
      float bgl = bias_s[gg];
      const u16* Kb = Kl[it & 1];
      const u16* Vb = Vl[it & 1];

      f32x4 s0v = {0,0,0,0}, s1v = {0,0,0,0};
      __builtin_amdgcn_s_setprio(1);
      #pragma unroll
      for (int kk = 0; kk < 8; ++kk) {
        int off = lo4*256 + 32*(kk ^ kxb) + kswz;
        bf16x8 kb0 = *(const bf16x8*)&Kb[off];
        bf16x8 kb1 = *(const bf16x8*)&Kb[off + 16*256];
        s0v = __builtin_amdgcn_mfma_f32_16x16x32_bf16(qf[kk], kb0, s0v, 0, 0, 0);
        s1v = __builtin_amdgcn_mfma_f32_16x16x32_bf16(qf[kk], kb1, s1v, 0, 0, 0);
      }
      __builtin_amdgcn_s_setprio(0);
      bool v0 = (tok0 + lo4) < 261, v1 = (tok0 + 16 + lo4) < 261;
      float p0[4], p1[4];
      #pragma unroll
      for (int r = 0; r < 4; ++r) {
        float e0 = __builtin_exp2f(fmaf(s0v[r], SC, bgl));
        float e1 = __builtin_exp2f(fmaf(s1v[r], SC, bgl));
        e0 = v0 ? e0 : 0.f;
        e1 = v1 ? e1 : 0.f;
        srun[r] += e0 + e1;
        p0[r] = e0; p1[r] = e1;
      }
      u16* Pw = Pl[wid];
      #pragma unroll
      for (int r = 0; r < 4; ++r) {
        Pw[(hi2*4 + r)*50 + lo4]      = f2bf(p0[r]);
        Pw[(hi2*4 + r)*50 + 16 + lo4] = f2bf(p1[r]);
      }
      bf16x8 pa = *(const bf16x8*)&Pw[lo4*50 + hi2*8];
      __builtin_amdgcn_s_setprio(1);
      #pragma unroll
      for (int o = 0; o < 16; ++o) {
        bf16x8 vv = *(const bf16x8*)&Vb[(o*16 + lo4)*32 + vswz];
        O[o] = __builtin_amdgcn_mfma_f32_16x16x32_bf16(pa, vv, O[o], 0, 0, 0);
      }
      __builtin_amdgcn_s_setprio(0);
    }
  }

  #pragma unroll
  for (int r = 0; r < 4; ++r) {
    float s = srun[r];
    s += __shfl_xor(s, 1);
    s += __shfl_xor(s, 2);
    s += __shfl_xor(s, 4);
    s += __shfl_xor(s, 8);
    srun[r] = 1.0f / s;
  }
  #pragma unroll
  for (int o = 0; o < 16; ++o) {
    #pragma unroll
    for (int r = 0; r < 4; ++r) {
      int qq = wid*16 + hi2*4 + r;
      AO[(size_t)(m*261 + qq) * CD + h*256 + o*16 + lo4] = f2bf(O[o][r] * srun[r]);
    }
  }
}

// Tail: rows 256..260 per (h,m).
__global__ __launch_bounds__(256) void attn_tail(
    const u16* __restrict__ QK, const u16* __restrict__ VtG,
    const float* __restrict__ bias, const int* __restrict__ idx,
    u16* __restrict__ AO)
{
  int h = blockIdx.x, m = blockIdx.y;
  int tid = threadIdx.x, lane = tid & 63, wid = tid >> 6;
  int lo4 = lane & 15, hi2 = lane >> 4;

  __shared__ float Om[4][16][256];
  __shared__ float Sm[4][16];
  __shared__ u16 Pl[4][16 * 50];

  int q = 256 + lo4;
  bool qv = q < 261;
  int qrow = m*261 + (qv ? q : 0);
  bf16x8 qf[8];
  #pragma unroll
  for (int kk = 0; kk < 8; ++kk) {
    u16x8 u = {0,0,0,0,0,0,0,0};
    if (qv) u = *(const u16x8*)&QK[(size_t)qrow * 4096 + h*256 + kk*32 + hi2*8];
    qf[kk] = __builtin_bit_cast(bf16x8, u);
  }

  f32x4 O[16] = {};
  float srun[4] = {0.f, 0.f, 0.f, 0.f};
  const float SC = 0.09016844f;

  for (int it = wid; it < 72; it += 4) {
    int gg = it / 9;
    int tok0 = (it - gg*9) * 32;
    int ig = idx[m*8 + gg];
    float bgl = bias[m*8 + gg] * 1.4426950408889634f;
    const u16* kbase = QK + (size_t)(ig*261 + tok0) * 4096 + 2048 + h*256;
    f32x4 s0v = {0,0,0,0}, s1v = {0,0,0,0};
    #pragma unroll
    for (int kk = 0; kk < 8; ++kk) {
      bf16x8 kb0 = *(const bf16x8*)&kbase[(size_t)lo4 * 4096 + kk*32 + hi2*8];
      bf16x8 kb1 = *(const bf16x8*)&kbase[(size_t)(16 + lo4) * 4096 + kk*32 + hi2*8];
      s0v = __builtin_amdgcn_mfma_f32_16x16x32_bf16(qf[kk], kb0, s0v, 0, 0, 0);
      s1v = __builtin_amdgcn_mfma_f32_16x16x32_bf16(qf[kk], kb1, s1v, 0, 0, 0);
    }
    bool v0 = (tok0 + lo4) < 261, v1 = (tok0 + 16 + lo4) < 261;
    float p0[4], p1[4];
    #pragma unroll
    for (int r = 0; r < 4; ++r) {
      float e0 = __builtin_exp2f(fmaf(s0v[r], SC, bgl));
      float e1 = __builtin_exp2f(fmaf(s1v[r], SC, bgl));
      e0 = v0 ? e0 : 0.f;
      e1 = v1 ? e1 : 0.f;
      srun[r] += e0 + e1;
      p0[r] = e0; p1[r] = e1;
    }
    u16* Pw = Pl[wid];
    #pragma unroll
    for (int r = 0; r < 4; ++r) {
      Pw[(hi2*4 + r)*50 + lo4]      = f2bf(p0[r]);
      Pw[(hi2*4 + r)*50 + 16 + lo4] = f2bf(p1[r]);
    }
    bf16x8 pa = *(const bf16x8*)&Pw[lo4*50 + hi2*8];
    const u16* vbase = VtG + (size_t)(h*256) * VTC + ig*264 + tok0;
    #pragma unroll
    for (int o = 0; o < 16; ++o) {
      bf16x8 vv = *(const bf16x8*)&vbase[(size_t)(o*16 + lo4) * VTC + hi2*8];
      O[o] = __builtin_amdgcn_mfma_f32_16x16x32_bf16(pa, vv, O[o], 0, 0, 0);
    }
  }

  #pragma unroll
  for (int r = 0; r < 4; ++r) {
    float s = srun[r];
    s += __shfl_xor(s, 1);
    s += __shfl_xor(s, 2);
    s += __shfl_xor(s, 4);
    s += __shfl_xor(s, 8);
    srun[r] = s;
  }
  #pragma unroll
  for (int o = 0; o < 16; ++o)
    #pragma unroll
    for (int r = 0; r < 4; ++r)
      Om[wid][hi2*4 + r][o*16 + lo4] = O[o][r];
  if (lo4 == 0) {
    #pragma unroll
    for (int r = 0; r < 4; ++r) Sm[wid][hi2*4 + r] = srun[r];
  }
  __syncthreads();
  if (wid == 0) {
    #pragma unroll
    for (int o = 0; o < 16; ++o) {
      #pragma unroll
      for (int r = 0; r < 4; ++r) {
        int row = hi2*4 + r;
        int qq = 256 + row;
        if (qq < 261) {
          int c = o*16 + lo4;
          float v = Om[0][row][c] + Om[1][row][c] + Om[2][row][c] + Om[3][row][c];
          float s = Sm[0][row] + Sm[1][row] + Sm[2][row] + Sm[3][row];
          AO[(size_t)(m*261 + qq) * CD + h*256 + c] = f2bf(v / s);
        }
      }
    }
  }
}

// ---------------- launch ----------------
extern "C" void kernel_launch(void* const* d_in, const int* in_sizes, int n_in,
                              void* d_out, int out_size, void* d_ws, size_t ws_size,
                              hipStream_t stream) {
  const float* tokens = (const float*)d_in[0];
  const float* Wq = (const float*)d_in[1];
  const float* Wk = (const float*)d_in[2];
  const float* Wv = (const float*)d_in[3];
  const float* Wo = (const float*)d_in[4];
  float* out = (float*)d_out;
  char* ws = (char*)d_ws;

  constexpr size_t OFF_TOKBF = 0;
  constexpr size_t OFF_WQKVT = OFF_TOKBF + (size_t)MPAD * CD * 2;
  constexpr size_t OFF_WOT   = OFF_WQKVT + (size_t)6144 * CD * 2;
  constexpr size_t OFF_QK    = OFF_WOT   + (size_t)CD * CD * 2;
  constexpr size_t OFF_VTG   = OFF_QK    + (size_t)MPAD * 4096 * 2;
  constexpr size_t OFF_AO    = OFF_VTG   + (size_t)CD * VTC * 2 + 4096; // +OOB slack
  constexpr size_t OFF_SIM   = OFF_AO    + (size_t)MPAD * CD * 2;
  constexpr size_t OFF_BIAS  = OFF_SIM   + 4096;
  constexpr size_t OFF_IDX   = OFF_BIAS  + 1024;

  u16* tokBf  = (u16*)(ws + OFF_TOKBF);
  u16* WqkvT  = (u16*)(ws + OFF_WQKVT);
  u16* WoT    = (u16*)(ws + OFF_WOT);
  u16* QKbuf  = (u16*)(ws + OFF_QK);
  u16* VtG    = (u16*)(ws + OFF_VTG);
  u16* attnO  = (u16*)(ws + OFF_AO);
  float* simw = (float*)(ws + OFF_SIM);
  float* bw   = (float*)(ws + OFF_BIAS);
  int*   iw   = (int*)(ws + OFF_IDX);

  cvt_tokens<<<MPAD, 256, 0, stream>>>(tokens, tokBf);
  cvt_w<<<dim3(64, 256), dim3(32, 8), 0, stream>>>(Wq, Wk, Wv, Wo, WqkvT, WoT);
  posesim<<<dim3(30, 30), 256, 0, stream>>>(tokens, simw);
  topk_bias<<<1, 32, 0, stream>>>(simw, bw, iw);
  gemm_bt<0><<<dim3(24, 31), 512, 0, stream>>>(tokBf, WqkvT, QKbuf, VtG, nullptr, nullptr, CD);
  attn_tail<<<dim3(8, 30), 256, 0, stream>>>(QKbuf, VtG, bw, iw, attnO);
  attn_main<<<dim3(8, 30), 1024, 0, stream>>>(QKbuf, VtG, bw, iw, attnO);
  gemm_bt<1><<<dim3(8, 31), 512, 0, stream>>>(attnO, WoT, nullptr, nullptr, tokens, out, CD);
}

// Round 8
// 640.394 us; speedup vs baseline: 1.1615x; 1.1615x over previous
//
#include <hip/hip_runtime.h>
#include <stdint.h>

#define MTOK 7830      // 30*261 valid token rows
#define MPAD 7936      // padded to 31*256
#define CD   2048
#define VTC  7920      // 30*264 (per-group padded token columns for V^T)
#define AS1 __attribute__((address_space(1)))
#define AS3 __attribute__((address_space(3)))

typedef unsigned short u16;
typedef __bf16 bf16x8 __attribute__((ext_vector_type(8)));
typedef float f32x4 __attribute__((ext_vector_type(4)));
typedef unsigned short u16x8 __attribute__((ext_vector_type(8)));

__device__ __forceinline__ u16 f2bf(float f) {
  unsigned x = __float_as_uint(f);
  return (u16)((x + 0x7fffu + ((x >> 16) & 1u)) >> 16);
}

__device__ __forceinline__ void gld16(const u16* g, u16* l) {
  __builtin_amdgcn_global_load_lds((AS1 const unsigned int*)(g), (AS3 unsigned int*)(l), 16, 0, 0);
}

// ---------------- converts ----------------
__global__ void cvt_tokens(const float* __restrict__ T, u16* __restrict__ O) {
  int row = blockIdx.x;
  size_t base = (size_t)row * CD + threadIdx.x * 8;
  u16x8 o = {0,0,0,0,0,0,0,0};
  if (row < MTOK) {
    const float* s = T + base;
    #pragma unroll
    for (int j = 0; j < 8; ++j) o[j] = f2bf(s[j]);
  }
  *(u16x8*)&O[base] = o;
}

__global__ void cvt_w(const float* __restrict__ Wq, const float* __restrict__ Wk,
                      const float* __restrict__ Wv, const float* __restrict__ Wo,
                      u16* __restrict__ WqkvT, u16* __restrict__ WoT) {
  __shared__ float tile[32][33];
  int k0 = blockIdx.x * 32;
  int n0 = blockIdx.y * 32;
  const float* W; u16* Dst; int nl0, dr0;
  if (n0 < 2048)      { W = Wq; Dst = WqkvT; nl0 = n0;        dr0 = n0; }
  else if (n0 < 4096) { W = Wk; Dst = WqkvT; nl0 = n0 - 2048; dr0 = n0; }
  else if (n0 < 6144) { W = Wv; Dst = WqkvT; nl0 = n0 - 4096; dr0 = n0; }
  else                { W = Wo; Dst = WoT;   nl0 = n0 - 6144; dr0 = n0 - 6144; }
  int tx = threadIdx.x, ty = threadIdx.y;
  #pragma unroll
  for (int i = 0; i < 4; ++i)
    tile[ty + i*8][tx] = W[(size_t)(k0 + ty + i*8) * CD + nl0 + tx];
  __syncthreads();
  #pragma unroll
  for (int i = 0; i < 4; ++i) {
    int n = ty + i*8;
    Dst[(size_t)(dr0 + n) * CD + k0 + tx] = f2bf(tile[tx][n]);
  }
}

// ---------------- pose similarity + topk ----------------
__global__ void posesim(const float* __restrict__ tok, float* __restrict__ sim) {
  int mm = blockIdx.y, nn = blockIdx.x;
  const float* a = tok + (size_t)mm * 261 * CD;
  const float* b = tok + (size_t)nn * 261 * CD;
  int tid = threadIdx.x;
  float p = 0.f;
  for (int j = tid; j < CD; j += 256) p += a[j] * b[j];
  __shared__ float red[256];
  red[tid] = p; __syncthreads();
  for (int s = 128; s > 0; s >>= 1) { if (tid < s) red[tid] += red[tid + s]; __syncthreads(); }
  if (tid == 0) sim[mm*30 + nn] = red[0] + (((mm/5) == (nn/5)) ? 10000.0f : 0.0f);
}

__global__ void topk_bias(const float* __restrict__ sim, float* __restrict__ bias,
                          int* __restrict__ idxo) {
  int m = threadIdx.x;
  if (m >= 30) return;
  float p[30];
  float mx = -1e30f;
  for (int j = 0; j < 30; ++j) { p[j] = sim[m*30 + j]; mx = fmaxf(mx, p[j]); }
  float z = 0.f;
  for (int j = 0; j < 30; ++j) { p[j] = __expf(p[j] - mx); z += p[j]; }
  float inv = 1.0f / z;
  for (int j = 0; j < 30; ++j) p[j] *= inv;
  for (int k = 0; k < 8; ++k) {
    int bj = 0; float bv = p[0];
    for (int j = 1; j < 30; ++j) if (p[j] > bv) { bv = p[j]; bj = j; }
    idxo[m*8 + k] = bj;
    bias[m*8 + k] = logf(bv + 1e-6f);
    p[bj] = -1.0f;
  }
}

// ---------------- GEMM v3 (R6, proven): 256x256, BK=64, counted-vmcnt pipeline ----
template<int EPI>
__global__ __launch_bounds__(512) void gemm_bt(
    const u16* __restrict__ A, const u16* __restrict__ Bt,
    u16* __restrict__ Cq, u16* __restrict__ Cv,
    const float* __restrict__ resid, float* __restrict__ Dout, int K)
{
  __shared__ u16 Al[2][256 * 64];
  __shared__ u16 Bl[2][256 * 64];
  int tid = threadIdx.x, lane = tid & 63, wid = tid >> 6;   // wid 0..7
  int lo4 = lane & 15, hi2 = lane >> 4;
  // bijective XCD swizzle (nwg % 8 == 0 for both instantiations)
  int lin = blockIdx.y * gridDim.x + blockIdx.x;
  int q8  = (gridDim.x * gridDim.y) >> 3;
  int lin2 = (lin & 7) * q8 + (lin >> 3);
  int bn = lin2 % gridDim.x, bm = lin2 / gridDim.x;
  int wy = wid >> 2, wx = wid & 3;          // 2M x 4N wave grid
  int r8 = lane >> 3, c8 = lane & 7;

  f32x4 acc[8][4] = {};

  size_t aofs[4], bofs[4];
  #pragma unroll
  for (int j = 0; j < 4; ++j) {
    int row = wid*32 + j*8 + r8;
    int sw = 8 * (c8 ^ (row & 7));          // XOR-swizzled source, linear LDS dst
    aofs[j] = (size_t)(bm*256 + row) * K + sw;
    bofs[j] = (size_t)(bn*256 + row) * K + sw;
  }
  int ldst = wid * 2048;

  int nK = K >> 6;
  // prologue: stage tiles 0 and 1
  #pragma unroll
  for (int j = 0; j < 4; ++j) {
    gld16(A  + aofs[j], &Al[0][ldst + j*512]);
    gld16(Bt + bofs[j], &Bl[0][ldst + j*512]);
  }
  #pragma unroll
  for (int j = 0; j < 4; ++j) {
    gld16(A  + 64 + aofs[j], &Al[1][ldst + j*512]);
    gld16(Bt + 64 + bofs[j], &Bl[1][ldst + j*512]);
  }

  for (int t = 0; t < nK; ++t) {
    if (t + 1 < nK) asm volatile("s_waitcnt vmcnt(8)" ::: "memory");
    else            asm volatile("s_waitcnt vmcnt(0)" ::: "memory");
    __builtin_amdgcn_sched_barrier(0);
    __builtin_amdgcn_s_barrier();
    __builtin_amdgcn_sched_barrier(0);

    const u16* Ac = Al[t & 1];
    const u16* Bc = Bl[t & 1];

    bf16x8 bv[4][2];
    #pragma unroll
    for (int ni = 0; ni < 4; ++ni) {
      int br = wx*64 + ni*16 + lo4;
      #pragma unroll
      for (int kk = 0; kk < 2; ++kk)
        bv[ni][kk] = *(const bf16x8*)&Bc[br*64 + 8*((kk*4 + hi2) ^ (br & 7))];
    }

    #pragma unroll
    for (int mg = 0; mg < 2; ++mg) {
      bf16x8 av[4][2];
      #pragma unroll
      for (int mi = 0; mi < 4; ++mi) {
        int ar = wy*128 + mg*64 + mi*16 + lo4;
        #pragma unroll
        for (int kk = 0; kk < 2; ++kk)
          av[mi][kk] = *(const bf16x8*)&Ac[ar*64 + 8*((kk*4 + hi2) ^ (ar & 7))];
      }
      __builtin_amdgcn_s_setprio(1);
      #pragma unroll
      for (int kk = 0; kk < 2; ++kk)
        #pragma unroll
        for (int mi = 0; mi < 4; ++mi)
          #pragma unroll
          for (int ni = 0; ni < 4; ++ni)
            acc[mg*4 + mi][ni] = __builtin_amdgcn_mfma_f32_16x16x32_bf16(
                av[mi][kk], bv[ni][kk], acc[mg*4 + mi][ni], 0, 0, 0);
      __builtin_amdgcn_s_setprio(0);
      if (mg == 0) {
        __builtin_amdgcn_s_barrier();
      } else {
        __builtin_amdgcn_sched_barrier(0);
        if (t + 2 < nK) {
          size_t kn = (size_t)(t + 2) << 6;
          u16* An = Al[t & 1];
          u16* Bn = Bl[t & 1];
          #pragma unroll
          for (int j = 0; j < 4; ++j) {
            gld16(A  + kn + aofs[j], &An[ldst + j*512]);
            gld16(Bt + kn + bofs[j], &Bn[ldst + j*512]);
          }
        }
        __builtin_amdgcn_sched_barrier(0);
      }
    }
  }

  int gm0 = bm*256 + wy*128;
  int gn0 = bn*256 + wx*64;
  #pragma unroll
  for (int mi = 0; mi < 8; ++mi) {
    #pragma unroll
    for (int ni = 0; ni < 4; ++ni) {
      int gmb = gm0 + mi*16 + hi2*4;
      int gn  = gn0 + ni*16 + lo4;
      #pragma unroll
      for (int r = 0; r < 4; ++r) {
        float v = acc[mi][ni][r];
        int gm = gmb + r;
        if (EPI == 0) {
          if (gn < 4096) {
            Cq[(size_t)gm * 4096 + gn] = f2bf(v);
          } else if (gm < MTOK) {
            int g = gm / 261, tk = gm - g * 261;
            Cv[(size_t)(gn - 4096) * VTC + g * 264 + tk] = f2bf(v);
          }
        } else {
          if (gm < MTOK) {
            size_t off = (size_t)gm * CD + gn;
            Dout[off] = resid[off] + v;
          }
        }
      }
    }
  }
}

// ---------------- fused neighbor attention v5 ----------------
// 8 waves x 32 q-rows: every K/V LDS fragment read feeds 2 MFMAs (2 q-groups),
// halving the LDS-read traffic that bounds this kernel.
__global__ __launch_bounds__(512) void attn_main(
    const u16* __restrict__ QK,   // [MPAD][4096] bf16 (Q 0..2047 | K 2048..4095)
    const u16* __restrict__ VtG,  // [2048][VTC] bf16 (V^T, per-group stride 264)
    const float* __restrict__ bias, const int* __restrict__ idx,
    u16* __restrict__ AO)         // [MPAD][2048] bf16
{
  int h = blockIdx.x, m = blockIdx.y;
  int tid = threadIdx.x, lane = tid & 63, wid = tid >> 6;   // wid 0..7
  int lo4 = lane & 15, hi2 = lane >> 4;

  __shared__ u16 Kl[2][32 * 256];
  __shared__ u16 Vl[2][256 * 32];
  __shared__ u16 Pl[8][2][16 * 50];
  __shared__ float bias_s[8];
  __shared__ int   idx_s[8];
  if (tid < 8) {
    bias_s[tid] = bias[m*8 + tid] * 1.4426950408889634f;
    idx_s[tid]  = idx[m*8 + tid];
  }

  // Q fragments: 32 rows per wave (2 groups of 16), rows wid*32..wid*32+31 < 256
  bf16x8 qf[2][8];
  #pragma unroll
  for (int qg = 0; qg < 2; ++qg) {
    int qrow = m*261 + wid*32 + qg*16 + lo4;
    #pragma unroll
    for (int kk = 0; kk < 8; ++kk)
      qf[qg][kk] = *(const bf16x8*)&QK[(size_t)qrow * 4096 + h*256 + kk*32 + hi2*8];
  }

  // staging: wave w stages K rows 4w..4w+3 and V d-rows 32w..32w+31 (2 gld16 each)
  size_t kofs[2], vofs[2];
  #pragma unroll
  for (int i = 0; i < 2; ++i) {
    int rt = 4*wid + 2*i + (lane >> 5);
    kofs[i] = (size_t)rt * 4096 + 2048 + h*256 + 8*((lane & 31) ^ (rt & 7));
    int vdr = 32*wid + 16*i + (lane >> 2);
    vofs[i] = (size_t)(h*256 + vdr) * VTC + 8*((lane & 3) ^ ((vdr >> 1) & 3));
  }
  int ld0 = wid * 1024;

  f32x4 O[2][16] = {};
  float srun[2][4] = {};
  const float SC = 0.09016844f;   // 0.0625 * log2(e)

  {
    int ig0 = idx[m*8];
    #pragma unroll
    for (int i = 0; i < 2; ++i) {
      gld16(QK + (size_t)(ig0*261) * 4096 + kofs[i], &Kl[0][ld0 + i*512]);
      gld16(VtG + (size_t)(ig0*264) + vofs[i],       &Vl[0][ld0 + i*512]);
    }
  }

  int vswz = 8 * (hi2 ^ ((lo4 >> 1) & 3));
  int kxb  = (lo4 >> 2) & 1;
  int kswz = 8 * (hi2 ^ (lo4 & 3));

  for (int it = 0; it < 72; ++it) {
    __syncthreads();
    if (it + 1 < 72) {
      int tn = it + 1;
      int gg = tn / 9;
      int tok0n = (tn - gg*9) * 32;
      int ign = idx_s[gg];
      #pragma unroll
      for (int i = 0; i < 2; ++i) {
        gld16(QK + (size_t)(ign*261 + tok0n) * 4096 + kofs[i], &Kl[tn & 1][ld0 + i*512]);
        gld16(VtG + (size_t)(ign*264 + tok0n) + vofs[i],       &Vl[tn & 1][ld0 + i*512]);
      }
    }
    {
      int gg = it / 9;
      int tok0 = (it - gg*9) * 32;
      float bgl = bias_s[gg];
      const u16* Kb = Kl[it & 1];
      const u16* Vb = Vl[it & 1];

      f32x4 sv[2][2] = {};
      __builtin_amdgcn_s_setprio(1);
      #pragma unroll
      for (int kk = 0; kk < 8; ++kk) {
        int off = lo4*256 + 32*(kk ^ kxb) + kswz;
        bf16x8 kb0 = *(const bf16x8*)&Kb[off];
        bf16x8 kb1 = *(const bf16x8*)&Kb[off + 16*256];
        sv[0][0] = __builtin_amdgcn_mfma_f32_16x16x32_bf16(qf[0][kk], kb0, sv[0][0], 0, 0, 0);
        sv[0][1] = __builtin_amdgcn_mfma_f32_16x16x32_bf16(qf[0][kk], kb1, sv[0][1], 0, 0, 0);
        sv[1][0] = __builtin_amdgcn_mfma_f32_16x16x32_bf16(qf[1][kk], kb0, sv[1][0], 0, 0, 0);
        sv[1][1] = __builtin_amdgcn_mfma_f32_16x16x32_bf16(qf[1][kk], kb1, sv[1][1], 0, 0, 0);
      }
      __builtin_amdgcn_s_setprio(0);
      bool v0 = (tok0 + lo4) < 261, v1 = (tok0 + 16 + lo4) < 261;
      #pragma unroll
      for (int qg = 0; qg < 2; ++qg) {
        u16* Pw = Pl[wid][qg];
        #pragma unroll
        for (int r = 0; r < 4; ++r) {
          float e0 = __builtin_exp2f(fmaf(sv[qg][0][r], SC, bgl));
          float e1 = __builtin_exp2f(fmaf(sv[qg][1][r], SC, bgl));
          e0 = v0 ? e0 : 0.f;
          e1 = v1 ? e1 : 0.f;
          srun[qg][r] += e0 + e1;
          Pw[(hi2*4 + r)*50 + lo4]      = f2bf(e0);
          Pw[(hi2*4 + r)*50 + 16 + lo4] = f2bf(e1);
        }
      }
      bf16x8 pa0 = *(const bf16x8*)&Pl[wid][0][lo4*50 + hi2*8];
      bf16x8 pa1 = *(const bf16x8*)&Pl[wid][1][lo4*50 + hi2*8];
      __builtin_amdgcn_s_setprio(1);
      #pragma unroll
      for (int o = 0; o < 16; ++o) {
        bf16x8 vv = *(const bf16x8*)&Vb[(o*16 + lo4)*32 + vswz];
        O[0][o] = __builtin_amdgcn_mfma_f32_16x16x32_bf16(pa0, vv, O[0][o], 0, 0, 0);
        O[1][o] = __builtin_amdgcn_mfma_f32_16x16x32_bf16(pa1, vv, O[1][o], 0, 0, 0);
      }
      __builtin_amdgcn_s_setprio(0);
    }
  }

  #pragma unroll
  for (int qg = 0; qg < 2; ++qg) {
    float inv[4];
    #pragma unroll
    for (int r = 0; r < 4; ++r) {
      float s = srun[qg][r];
      s += __shfl_xor(s, 1);
      s += __shfl_xor(s, 2);
      s += __shfl_xor(s, 4);
      s += __shfl_xor(s, 8);
      inv[r] = 1.0f / s;
    }
    #pragma unroll
    for (int o = 0; o < 16; ++o) {
      #pragma unroll
      for (int r = 0; r < 4; ++r) {
        int qq = wid*32 + qg*16 + hi2*4 + r;   // < 256, always valid
        AO[(size_t)(m*261 + qq) * CD + h*256 + o*16 + lo4] = f2bf(O[qg][o][r] * inv[r]);
      }
    }
  }
}

// Tail: rows 256..260 per (h,m).
__global__ __launch_bounds__(256) void attn_tail(
    const u16* __restrict__ QK, const u16* __restrict__ VtG,
    const float* __restrict__ bias, const int* __restrict__ idx,
    u16* __restrict__ AO)
{
  int h = blockIdx.x, m = blockIdx.y;
  int tid = threadIdx.x, lane = tid & 63, wid = tid >> 6;
  int lo4 = lane & 15, hi2 = lane >> 4;

  __shared__ float Om[4][16][256];
  __shared__ float Sm[4][16];
  __shared__ u16 Pl[4][16 * 50];

  int q = 256 + lo4;
  bool qv = q < 261;
  int qrow = m*261 + (qv ? q : 0);
  bf16x8 qf[8];
  #pragma unroll
  for (int kk = 0; kk < 8; ++kk) {
    u16x8 u = {0,0,0,0,0,0,0,0};
    if (qv) u = *(const u16x8*)&QK[(size_t)qrow * 4096 + h*256 + kk*32 + hi2*8];
    qf[kk] = __builtin_bit_cast(bf16x8, u);
  }

  f32x4 O[16] = {};
  float srun[4] = {0.f, 0.f, 0.f, 0.f};
  const float SC = 0.09016844f;

  for (int it = wid; it < 72; it += 4) {
    int gg = it / 9;
    int tok0 = (it - gg*9) * 32;
    int ig = idx[m*8 + gg];
    float bgl = bias[m*8 + gg] * 1.4426950408889634f;
    const u16* kbase = QK + (size_t)(ig*261 + tok0) * 4096 + 2048 + h*256;
    f32x4 s0v = {0,0,0,0}, s1v = {0,0,0,0};
    #pragma unroll
    for (int kk = 0; kk < 8; ++kk) {
      bf16x8 kb0 = *(const bf16x8*)&kbase[(size_t)lo4 * 4096 + kk*32 + hi2*8];
      bf16x8 kb1 = *(const bf16x8*)&kbase[(size_t)(16 + lo4) * 4096 + kk*32 + hi2*8];
      s0v = __builtin_amdgcn_mfma_f32_16x16x32_bf16(qf[kk], kb0, s0v, 0, 0, 0);
      s1v = __builtin_amdgcn_mfma_f32_16x16x32_bf16(qf[kk], kb1, s1v, 0, 0, 0);
    }
    bool v0 = (tok0 + lo4) < 261, v1 = (tok0 + 16 + lo4) < 261;
    float p0[4], p1[4];
    #pragma unroll
    for (int r = 0; r < 4; ++r) {
      float e0 = __builtin_exp2f(fmaf(s0v[r], SC, bgl));
      float e1 = __builtin_exp2f(fmaf(s1v[r], SC, bgl));
      e0 = v0 ? e0 : 0.f;
      e1 = v1 ? e1 : 0.f;
      srun[r] += e0 + e1;
      p0[r] = e0; p1[r] = e1;
    }
    u16* Pw = Pl[wid];
    #pragma unroll
    for (int r = 0; r < 4; ++r) {
      Pw[(hi2*4 + r)*50 + lo4]      = f2bf(p0[r]);
      Pw[(hi2*4 + r)*50 + 16 + lo4] = f2bf(p1[r]);
    }
    bf16x8 pa = *(const bf16x8*)&Pw[lo4*50 + hi2*8];
    const u16* vbase = VtG + (size_t)(h*256) * VTC + ig*264 + tok0;
    #pragma unroll
    for (int o = 0; o < 16; ++o) {
      bf16x8 vv = *(const bf16x8*)&vbase[(size_t)(o*16 + lo4) * VTC + hi2*8];
      O[o] = __builtin_amdgcn_mfma_f32_16x16x32_bf16(pa, vv, O[o], 0, 0, 0);
    }
  }

  #pragma unroll
  for (int r = 0; r < 4; ++r) {
    float s = srun[r];
    s += __shfl_xor(s, 1);
    s += __shfl_xor(s, 2);
    s += __shfl_xor(s, 4);
    s += __shfl_xor(s, 8);
    srun[r] = s;
  }
  #pragma unroll
  for (int o = 0; o < 16; ++o)
    #pragma unroll
    for (int r = 0; r < 4; ++r)
      Om[wid][hi2*4 + r][o*16 + lo4] = O[o][r];
  if (lo4 == 0) {
    #pragma unroll
    for (int r = 0; r < 4; ++r) Sm[wid][hi2*4 + r] = srun[r];
  }
  __syncthreads();
  if (wid == 0) {
    #pragma unroll
    for (int o = 0; o < 16; ++o) {
      #pragma unroll
      for (int r = 0; r < 4; ++r) {
        int row = hi2*4 + r;
        int qq = 256 + row;
        if (qq < 261) {
          int c = o*16 + lo4;
          float v = Om[0][row][c] + Om[1][row][c] + Om[2][row][c] + Om[3][row][c];
          float s = Sm[0][row] + Sm[1][row] + Sm[2][row] + Sm[3][row];
          AO[(size_t)(m*261 + qq) * CD + h*256 + c] = f2bf(v / s);
        }
      }
    }
  }
}

// ---------------- launch ----------------
extern "C" void kernel_launch(void* const* d_in, const int* in_sizes, int n_in,
                              void* d_out, int out_size, void* d_ws, size_t ws_size,
                              hipStream_t stream) {
  const float* tokens = (const float*)d_in[0];
  const float* Wq = (const float*)d_in[1];
  const float* Wk = (const float*)d_in[2];
  const float* Wv = (const float*)d_in[3];
  const float* Wo = (const float*)d_in[4];
  float* out = (float*)d_out;
  char* ws = (char*)d_ws;

  constexpr size_t OFF_TOKBF = 0;
  constexpr size_t OFF_WQKVT = OFF_TOKBF + (size_t)MPAD * CD * 2;
  constexpr size_t OFF_WOT   = OFF_WQKVT + (size_t)6144 * CD * 2;
  constexpr size_t OFF_QK    = OFF_WOT   + (size_t)CD * CD * 2;
  constexpr size_t OFF_VTG   = OFF_QK    + (size_t)MPAD * 4096 * 2;
  constexpr size_t OFF_AO    = OFF_VTG   + (size_t)CD * VTC * 2 + 4096; // +OOB slack
  constexpr size_t OFF_SIM   = OFF_AO    + (size_t)MPAD * CD * 2;
  constexpr size_t OFF_BIAS  = OFF_SIM   + 4096;
  constexpr size_t OFF_IDX   = OFF_BIAS  + 1024;

  u16* tokBf  = (u16*)(ws + OFF_TOKBF);
  u16* WqkvT  = (u16*)(ws + OFF_WQKVT);
  u16* WoT    = (u16*)(ws + OFF_WOT);
  u16* QKbuf  = (u16*)(ws + OFF_QK);
  u16* VtG    = (u16*)(ws + OFF_VTG);
  u16* attnO  = (u16*)(ws + OFF_AO);
  float* simw = (float*)(ws + OFF_SIM);
  float* bw   = (float*)(ws + OFF_BIAS);
  int*   iw   = (int*)(ws + OFF_IDX);

  cvt_tokens<<<MPAD, 256, 0, stream>>>(tokens, tokBf);
  cvt_w<<<dim3(64, 256), dim3(32, 8), 0, stream>>>(Wq, Wk, Wv, Wo, WqkvT, WoT);
  posesim<<<dim3(30, 30), 256, 0, stream>>>(tokens, simw);
  topk_bias<<<1, 32, 0, stream>>>(simw, bw, iw);
  gemm_bt<0><<<dim3(24, 31), 512, 0, stream>>>(tokBf, WqkvT, QKbuf, VtG, nullptr, nullptr, CD);
  attn_tail<<<dim3(8, 30), 256, 0, stream>>>(QKbuf, VtG, bw, iw, attnO);
  attn_main<<<dim3(8, 30), 512, 0, stream>>>(QKbuf, VtG, bw, iw, attnO);
  gemm_bt<1><<<dim3(8, 31), 512, 0, stream>>>(attnO, WoT, nullptr, nullptr, tokens, out, CD);
}